// Round 5
// baseline (85.832 us; speedup 1.0000x reference)
//
#include <hip/hip_runtime.h>

// ---------------------------------------------------------------------------
// Chamfer_Loss: chamfer(pred,tgt) + W_EDGE*edge + W_LAP*cotLap + W_NORMAL*nc
//               + W_VEL*chamfer(diff(pred), diff(tgt))
// B=2, N=8281 (g=91), fp32 in/out. Output: 1 scalar.
// R5: explicit 4-deep LDS prefetch in the chamfer inner loop (R4 stalled on
//     single-outstanding ds_read: VGPR=40 showed compiler kept 1 y-buffer),
//     min3-fused min updates (3.5 ops/eval), sy padded +4 for pipeline tail.
// ---------------------------------------------------------------------------

#define W_EDGE   0.5f
#define W_LAP    0.05f
#define W_NORMAL 0.01f
#define W_VEL    10.0f

#define NX  7          // x points per thread (registers)
#define TPB 128        // threads per chamfer block
#define YT  256        // y tile size (compile-time inner trip count)

__device__ __forceinline__ float wave_sum(float v) {
#pragma unroll
    for (int o = 32; o > 0; o >>= 1) v += __shfl_down(v, o, 64);
    return v;
}

// Zero [accum | Lx | rowsum] and set the 4 min arrays to +big.
__global__ void init_ws_k(float* __restrict__ ws, int nzero, int ninf)
{
    unsigned int* w = (unsigned int*)ws;
    const int total = nzero + ninf;
    for (int i = blockIdx.x * blockDim.x + threadIdx.x; i < total;
         i += gridDim.x * blockDim.x)
        w[i] = (i < nzero) ? 0u : 0x7F7F7F7Fu;   // 3.39e38f
}

// All 4 chamfer direction/shift/batch combos in one dispatch.
// blockIdx.z = variant*2 + b, variant: 0 pred->tgt, 1 tgt->pred,
//                                      2 dpred->dtgt, 3 dtgt->dpred.
// mins layout: [B*N minA][B*N minB][B*N1 minC][B*N1 minD]
__global__ __launch_bounds__(TPB)
void chamfer_all_k(const float* __restrict__ pred, const float* __restrict__ tgt,
                   int N, unsigned int* __restrict__ mins)
{
    const int variant = blockIdx.z >> 1;
    const int b       = blockIdx.z & 1;
    const int shift   = variant >> 1;
    const int Np      = N - shift;
    const int N1      = N - 1;

    const float* __restrict__ xb = ((variant & 1) == 0 ? pred : tgt) + (size_t)b * N * 3;
    const float* __restrict__ yb = ((variant & 1) == 0 ? tgt : pred) + (size_t)b * N * 3;

    size_t off;
    if (variant == 0)      off = (size_t)b * N;
    else if (variant == 1) off = (size_t)2 * N + (size_t)b * N;          // B=2
    else if (variant == 2) off = (size_t)4 * N + (size_t)b * N1;
    else                   off = (size_t)4 * N + (size_t)2 * N1 + (size_t)b * N1;
    unsigned int* __restrict__ out = mins + off;

    const int base = blockIdx.x * (TPB * NX) + threadIdx.x;

    float xs0[NX], xs1[NX], xs2[NX], xx[NX], m[NX];
#pragma unroll
    for (int k = 0; k < NX; ++k) {
        const int gi = base + k * TPB;
        float a0 = 0.f, a1 = 0.f, a2 = 0.f;
        if (gi < Np) {
            if (shift) {
                a0 = xb[(gi + 1) * 3 + 0] - xb[gi * 3 + 0];
                a1 = xb[(gi + 1) * 3 + 1] - xb[gi * 3 + 1];
                a2 = xb[(gi + 1) * 3 + 2] - xb[gi * 3 + 2];
            } else {
                a0 = xb[gi * 3 + 0]; a1 = xb[gi * 3 + 1]; a2 = xb[gi * 3 + 2];
            }
        }
        xx[k]  = fmaf(a0, a0, fmaf(a1, a1, a2 * a2));
        xs0[k] = -2.0f * a0; xs1[k] = -2.0f * a1; xs2[k] = -2.0f * a2;
        m[k]   = 3.0e38f;
    }

    // stage one 256-y tile; pad with yy=+big (min-neutral); +4 for prefetch tail
    __shared__ float4 sy[YT + 4];
    const int ys = blockIdx.y * YT;
#pragma unroll
    for (int r = 0; r < YT / TPB; ++r) {
        const int j  = threadIdx.x + r * TPB;
        const int yi = ys + j;
        float4 v = make_float4(0.f, 0.f, 0.f, 3.0e38f);
        if (yi < Np) {
            float y0, y1, y2;
            if (shift) {
                y0 = yb[(yi + 1) * 3 + 0] - yb[yi * 3 + 0];
                y1 = yb[(yi + 1) * 3 + 1] - yb[yi * 3 + 1];
                y2 = yb[(yi + 1) * 3 + 2] - yb[yi * 3 + 2];
            } else {
                y0 = yb[yi * 3 + 0]; y1 = yb[yi * 3 + 1]; y2 = yb[yi * 3 + 2];
            }
            v = make_float4(y0, y1, y2, fmaf(y0, y0, fmaf(y1, y1, y2 * y2)));
        }
        sy[j] = v;
    }
    if (threadIdx.x < 4) sy[YT + threadIdx.x] = make_float4(0.f, 0.f, 0.f, 3.0e38f);
    __syncthreads();

    // software-pipelined inner loop: 4 y-points in compute, 4 in flight
    float4 y0 = sy[0], y1 = sy[1], y2 = sy[2], y3 = sy[3];
    for (int jj = 0; jj < YT; jj += 4) {
        const float4 n0 = sy[jj + 4], n1 = sy[jj + 5],
                     n2 = sy[jj + 6], n3 = sy[jj + 7];
#pragma unroll
        for (int k = 0; k < NX; ++k) {
            // u = yy - 2 x.y   (x pre-scaled by -2, yy folded into chain start)
            float u0 = fmaf(xs0[k], y0.x, fmaf(xs1[k], y0.y, fmaf(xs2[k], y0.z, y0.w)));
            float u1 = fmaf(xs0[k], y1.x, fmaf(xs1[k], y1.y, fmaf(xs2[k], y1.z, y1.w)));
            float u2 = fmaf(xs0[k], y2.x, fmaf(xs1[k], y2.y, fmaf(xs2[k], y2.z, y2.w)));
            float u3 = fmaf(xs0[k], y3.x, fmaf(xs1[k], y3.y, fmaf(xs2[k], y3.z, y3.w)));
            m[k] = fminf(fminf(m[k], u0), u1);   // -> v_min3_f32
            m[k] = fminf(fminf(m[k], u2), u3);   // -> v_min3_f32
        }
        y0 = n0; y1 = n1; y2 = n2; y3 = n3;
    }

#pragma unroll
    for (int k = 0; k < NX; ++k) {
        const int gi = base + k * TPB;
        if (gi < Np) {
            const float d = fmaxf(xx[k] + m[k], 0.0f);       // clamp like reference
            atomicMin(&out[gi], __float_as_uint(d));
        }
    }
}

// edge loss + normal consistency + laplacian cot scatter, one dispatch.
__global__ void mesh_k(const float* __restrict__ pred,
                       const int* __restrict__ edges, int E,
                       const int* __restrict__ pairs, int P,
                       const int* __restrict__ faces, int F,
                       int N, int B, float scaleE, float scaleP,
                       float* __restrict__ Lx, float* __restrict__ rowsum,
                       float* __restrict__ accum)
{
    const int tE = B * E, tP = B * P, tF = B * F;
    const int total = tE + tP + tF;
    float se = 0.f, sp = 0.f;
    for (int idx = blockIdx.x * blockDim.x + threadIdx.x; idx < total;
         idx += gridDim.x * blockDim.x) {
        if (idx < tE) {
            const int b = idx / E;
            const int e = idx - b * E;
            const float* __restrict__ vb = pred + (size_t)b * N * 3;
            const int i0 = edges[e * 2 + 0], i1 = edges[e * 2 + 1];
            float dx = vb[i0 * 3 + 0] - vb[i1 * 3 + 0];
            float dy = vb[i0 * 3 + 1] - vb[i1 * 3 + 1];
            float dz = vb[i0 * 3 + 2] - vb[i1 * 3 + 2];
            se += fmaf(dx, dx, fmaf(dy, dy, dz * dz));
        } else if (idx < tE + tP) {
            const int q = idx - tE;
            const int b = q / P;
            const int p = q - b * P;
            const float* __restrict__ vb = pred + (size_t)b * N * 3;
            const int a0 = pairs[p * 4 + 0], a1 = pairs[p * 4 + 1];
            const int a2 = pairs[p * 4 + 2], a3 = pairs[p * 4 + 3];
            float p0x = vb[a0 * 3], p0y = vb[a0 * 3 + 1], p0z = vb[a0 * 3 + 2];
            float ex = vb[a1 * 3] - p0x, ey = vb[a1 * 3 + 1] - p0y, ez = vb[a1 * 3 + 2] - p0z;
            float ux = vb[a2 * 3] - p0x, uy = vb[a2 * 3 + 1] - p0y, uz = vb[a2 * 3 + 2] - p0z;
            float wx = vb[a3 * 3] - p0x, wy = vb[a3 * 3 + 1] - p0y, wz = vb[a3 * 3 + 2] - p0z;
            float n0x = ey * uz - ez * uy;
            float n0y = ez * ux - ex * uz;
            float n0z = ex * uy - ey * ux;
            float n1x = -(ey * wz - ez * wy);
            float n1y = -(ez * wx - ex * wz);
            float n1z = -(ex * wy - ey * wx);
            float dt = n0x * n1x + n0y * n1y + n0z * n1z;
            float l0 = sqrtf(n0x * n0x + n0y * n0y + n0z * n0z);
            float l1 = sqrtf(n1x * n1x + n1y * n1y + n1z * n1z);
            sp += 1.0f - dt / (fmaxf(l0, 1e-8f) * fmaxf(l1, 1e-8f));
        } else {
            const int q = idx - tE - tP;
            const int b = q / F;
            const int f = q - b * F;
            const float* __restrict__ vb = pred + (size_t)b * N * 3;
            const int i0 = faces[f * 3 + 0], i1 = faces[f * 3 + 1], i2 = faces[f * 3 + 2];
            float v0x = vb[i0 * 3], v0y = vb[i0 * 3 + 1], v0z = vb[i0 * 3 + 2];
            float v1x = vb[i1 * 3], v1y = vb[i1 * 3 + 1], v1z = vb[i1 * 3 + 2];
            float v2x = vb[i2 * 3], v2y = vb[i2 * 3 + 1], v2z = vb[i2 * 3 + 2];
            float ax = v1x - v2x, ay = v1y - v2y, az = v1z - v2z;
            float bx = v0x - v2x, by = v0y - v2y, bz = v0z - v2z;
            float cx = v0x - v1x, cy = v0y - v1y, cz = v0z - v1z;
            float A  = sqrtf(ax * ax + ay * ay + az * az);
            float Bl = sqrtf(bx * bx + by * by + bz * bz);
            float C  = sqrtf(cx * cx + cy * cy + cz * cz);
            float s2 = 0.5f * (A + Bl + C);
            float area = sqrtf(fmaxf(s2 * (s2 - A) * (s2 - Bl) * (s2 - C), 1e-12f));
            float A2 = A * A, B2 = Bl * Bl, C2 = C * C;
            float inv4a = 1.0f / (4.0f * area);
            float cota = (B2 + C2 - A2) * inv4a;
            float cotb = (A2 + C2 - B2) * inv4a;
            float cotc = (A2 + B2 - C2) * inv4a;

            float* __restrict__ Lb = Lx + (size_t)b * N * 3;
            float* __restrict__ rb = rowsum + (size_t)b * N;
            // cot[k] symmetric on edge (ii[k],jj[k]): cota<->(1,2) cotb<->(2,0) cotc<->(0,1)
            #define SCAT(i, j, w)                                             \
                atomicAdd(&Lb[(i) * 3 + 0], (w) * vb[(j) * 3 + 0]);           \
                atomicAdd(&Lb[(i) * 3 + 1], (w) * vb[(j) * 3 + 1]);           \
                atomicAdd(&Lb[(i) * 3 + 2], (w) * vb[(j) * 3 + 2]);           \
                atomicAdd(&rb[(i)], (w));
            SCAT(i1, i2, cota) SCAT(i2, i1, cota)
            SCAT(i2, i0, cotb) SCAT(i0, i2, cotb)
            SCAT(i0, i1, cotc) SCAT(i1, i0, cotc)
            #undef SCAT
        }
    }
    se = wave_sum(se);
    sp = wave_sum(sp);
    if ((threadIdx.x & 63) == 0) atomicAdd(accum, fmaf(se, scaleE, sp * scaleP));
}

// chamfer mins reduction + laplacian residual norm, one dispatch.
__global__ void finalize_k(const unsigned int* __restrict__ mins, int lenN2, int lenN12,
                           float sA, float sC,
                           const float* __restrict__ pred, const float* __restrict__ Lx,
                           const float* __restrict__ rowsum, int N, int B, float scaleL,
                           float* __restrict__ accum)
{
    const int tM = lenN2 + lenN12;
    const int total = tM + B * N;
    float s1 = 0.f, s2 = 0.f, s3 = 0.f;
    for (int idx = blockIdx.x * blockDim.x + threadIdx.x; idx < total;
         idx += gridDim.x * blockDim.x) {
        if (idx < lenN2)      s1 += __uint_as_float(mins[idx]);
        else if (idx < tM)    s2 += __uint_as_float(mins[idx]);
        else {
            const int q = idx - tM;
            float rs = rowsum[q];
            float nw = rs > 0.f ? 1.0f / rs : 0.f;
            float rx = Lx[q * 3 + 0] * nw - pred[q * 3 + 0];
            float ry = Lx[q * 3 + 1] * nw - pred[q * 3 + 1];
            float rz = Lx[q * 3 + 2] * nw - pred[q * 3 + 2];
            s3 += sqrtf(rx * rx + ry * ry + rz * rz);
        }
    }
    s1 = wave_sum(s1);
    s2 = wave_sum(s2);
    s3 = wave_sum(s3);
    if ((threadIdx.x & 63) == 0)
        atomicAdd(accum, fmaf(s1, sA, fmaf(s2, sC, s3 * scaleL)));
}

__global__ void write_out_k(const float* __restrict__ accum, float* __restrict__ out)
{
    out[0] = accum[0];
}

extern "C" void kernel_launch(void* const* d_in, const int* in_sizes, int n_in,
                              void* d_out, int out_size, void* d_ws, size_t ws_size,
                              hipStream_t stream)
{
    const float* pred = (const float*)d_in[0];
    const float* tgt  = (const float*)d_in[1];
    const int* faces  = (const int*)d_in[2];
    const int* edges  = (const int*)d_in[3];
    const int* pairs  = (const int*)d_in[4];

    const int B = 2;
    const int N = in_sizes[0] / (3 * B);   // 8281
    const int F = in_sizes[2] / 3;         // 16200
    const int E = in_sizes[3] / 2;         // ~24480
    const int P = in_sizes[4] / 4;         // ~24120
    const int N1 = N - 1;

    // workspace layout (floats)
    float* ws       = (float*)d_ws;
    float* accum    = ws;                        // 8
    float* Lx       = ws + 8;                    // B*N*3
    float* rowsum   = Lx + (size_t)B * N * 3;    // B*N
    unsigned int* minsBase = (unsigned int*)(rowsum + (size_t)B * N); // 2*B*N + 2*B*N1

    const int nzero = 8 + B * N * 3 + B * N;
    const int ninf  = 2 * B * N + 2 * B * N1;

    init_ws_k<<<64, dim3(256), 0, stream>>>(ws, nzero, ninf);

    const dim3 gc((N + TPB * NX - 1) / (TPB * NX), (N + YT - 1) / YT, 4 * B);
    chamfer_all_k<<<gc, dim3(TPB), 0, stream>>>(pred, tgt, N, minsBase);

    mesh_k<<<128, dim3(256), 0, stream>>>(pred, edges, E, pairs, P, faces, F, N, B,
                                          W_EDGE / ((float)B * (float)E),
                                          W_NORMAL / ((float)B * (float)P),
                                          Lx, rowsum, accum);

    const float sBN  = 1.0f / ((float)B * (float)N);
    const float sBN1 = W_VEL / ((float)B * (float)N1);
    finalize_k<<<96, dim3(256), 0, stream>>>(minsBase, 2 * B * N, 2 * B * N1, sBN, sBN1,
                                             pred, Lx, rowsum, N, B,
                                             W_LAP / ((float)B * (float)N), accum);

    write_out_k<<<1, 1, 0, stream>>>(accum, (float*)d_out);
}